// Round 2
// baseline (1883.014 us; speedup 1.0000x reference)
//
#include <hip/hip_runtime.h>
#include <hip/hip_bf16.h>
#include <cstdint>
#include <cstddef>

// ---------------- constants ----------------
#define S_LEN  2048
#define HIDDEN 2304
#define NHEAD  8
#define NKVH   4
#define DHEAD  256
#define FFDIM  9216
#define QKVN   4096   // (H + 2*KV) * D
#define ODIM   2048   // H * D
#define WINM1  1023
#define QSCALE 0.0625f
#define CAPF   50.0f

typedef __attribute__((ext_vector_type(4))) float f32x4;
typedef __attribute__((ext_vector_type(8))) short s16x8;

// async global->LDS 16B copy; lptr must be wave-uniform, HW adds lane*16
__device__ __forceinline__ void gload_lds16(const void* gptr, void* lptr) {
  __builtin_amdgcn_global_load_lds(
      (const __attribute__((address_space(1))) unsigned int*)gptr,
      (__attribute__((address_space(3))) unsigned int*)lptr, 16, 0, 0);
}

__device__ __forceinline__ float bf16lo(uint32_t p) { return __uint_as_float(p << 16); }
__device__ __forceinline__ float bf16hi(uint32_t p) { return __uint_as_float(p & 0xffff0000u); }

// ---------------- diagnostic fill (ws too small): value encodes ws MiB ----------------
__global__ void k_fill(float* p, float v, size_t n) {
  size_t i = (size_t)blockIdx.x * blockDim.x + threadIdx.x;
  size_t st = (size_t)gridDim.x * blockDim.x;
  for (; i < n; i += st) p[i] = v;
}

// ---------------- f32 [R][C] -> bf16 [C][R] ----------------
__global__ void k_transpose_bf16(const float* __restrict__ in, __hip_bfloat16* __restrict__ out,
                                 int R, int C) {
  __shared__ float tile[32][33];
  const int c0 = blockIdx.x * 32, r0 = blockIdx.y * 32;
  const int tc = threadIdx.x & 31, tr = threadIdx.x >> 5;  // 32 x 8
#pragma unroll
  for (int i = 0; i < 4; i++)
    tile[tr + 8 * i][tc] = in[(size_t)(r0 + tr + 8 * i) * C + c0 + tc];
  __syncthreads();
#pragma unroll
  for (int i = 0; i < 4; i++)
    out[(size_t)(c0 + tr + 8 * i) * R + r0 + tc] = __float2bfloat16(tile[tc][tr + 8 * i]);
}

// ---------------- rmsnorm (row = 2304), optional residual add, f32/bf16 out ----------------
template <bool ADD, bool BF16OUT>
__global__ void k_rmsnorm(const float* __restrict__ x, const float* __restrict__ w,
                          const float* __restrict__ res, void* __restrict__ outv) {
  const int row = blockIdx.x;
  const float* xr = x + (size_t)row * HIDDEN;
  float ss = 0.f;
  for (int i = threadIdx.x; i < HIDDEN; i += 256) { float v = xr[i]; ss += v * v; }
#pragma unroll
  for (int off = 32; off >= 1; off >>= 1) ss += __shfl_down(ss, off);
  __shared__ float red[4];
  __shared__ float srstd;
  if ((threadIdx.x & 63) == 0) red[threadIdx.x >> 6] = ss;
  __syncthreads();
  if (threadIdx.x == 0) {
    float tot = red[0] + red[1] + red[2] + red[3];
    srstd = rsqrtf(tot / (float)HIDDEN + 1e-6f);
  }
  __syncthreads();
  const float rstd = srstd;
  for (int i = threadIdx.x; i < HIDDEN; i += 256) {
    float v = xr[i] * rstd * (1.f + w[i]);
    if constexpr (ADD) v += res[(size_t)row * HIDDEN + i];
    if constexpr (BF16OUT)
      ((__hip_bfloat16*)outv)[(size_t)row * HIDDEN + i] = __float2bfloat16(v);
    else
      ((float*)outv)[(size_t)row * HIDDEN + i] = v;
  }
}

// ---------------- bf16 GEMM: C[M][N] = A[M][K] * Bt[N][K]^T  (m97 structure) ----------------
// 128x128 tile, BK=64, 256 thr = 4 waves (2x2), each wave 64x64 = 4x4 frags of 16x16x32.
// EPI: 0 = f32 out; 1 = bf16 out; 2 = bf16 out, val = gelu_tanh(G[r][c]) * acc
template <int EPI>
__global__ __launch_bounds__(256) void k_gemm_bt(const __hip_bfloat16* __restrict__ A,
                                                 const __hip_bfloat16* __restrict__ Bt,
                                                 void* __restrict__ Cv,
                                                 const __hip_bfloat16* __restrict__ G,
                                                 int N, int K) {
  __shared__ alignas(16) __hip_bfloat16 sA[128 * 64];
  __shared__ alignas(16) __hip_bfloat16 sB[128 * 64];
  const int t = threadIdx.x;
  const int w = t >> 6;
  const int wm = w >> 1, wn = w & 1;
  const int m0 = blockIdx.y * 128, n0 = blockIdx.x * 128;
  const int lr = t & 15, lg = (t & 63) >> 4;   // frag row/col, k-group
  const int srow = t >> 3, sc8 = t & 7;        // staging: row-within-32-chunk, 8-elem col

  f32x4 acc[4][4];
#pragma unroll
  for (int a = 0; a < 4; a++)
#pragma unroll
    for (int b = 0; b < 4; b++) acc[a][b] = (f32x4){0.f, 0.f, 0.f, 0.f};

  for (int kt = 0; kt < K; kt += 64) {
#pragma unroll
    for (int i = 0; i < 4; i++) {
      const __hip_bfloat16* g = A + (size_t)(m0 + i * 32 + srow) * K + kt + sc8 * 8;
      gload_lds16(g, sA + (size_t)(i * 256 + w * 64) * 8);
    }
#pragma unroll
    for (int i = 0; i < 4; i++) {
      const __hip_bfloat16* g = Bt + (size_t)(n0 + i * 32 + srow) * K + kt + sc8 * 8;
      gload_lds16(g, sB + (size_t)(i * 256 + w * 64) * 8);
    }
    __syncthreads();  // drains vmcnt (global_load_lds) + lgkm
#pragma unroll
    for (int ks = 0; ks < 2; ks++) {
      s16x8 af[4], bfr[4];
#pragma unroll
      for (int fm = 0; fm < 4; fm++)
        af[fm] = *reinterpret_cast<const s16x8*>(sA + (wm * 64 + fm * 16 + lr) * 64 + ks * 32 + lg * 8);
#pragma unroll
      for (int fn = 0; fn < 4; fn++)
        bfr[fn] = *reinterpret_cast<const s16x8*>(sB + (wn * 64 + fn * 16 + lr) * 64 + ks * 32 + lg * 8);
#pragma unroll
      for (int fm = 0; fm < 4; fm++)
#pragma unroll
        for (int fn = 0; fn < 4; fn++)
          acc[fm][fn] = __builtin_amdgcn_mfma_f32_16x16x32_bf16(af[fm], bfr[fn], acc[fm][fn], 0, 0, 0);
    }
    __syncthreads();
  }
  // C/D layout (m89-verified): col = lane&15, row = (lane>>4)*4 + reg
#pragma unroll
  for (int fm = 0; fm < 4; fm++) {
    const int rb = m0 + wm * 64 + fm * 16 + lg * 4;
#pragma unroll
    for (int fn = 0; fn < 4; fn++) {
      const int col = n0 + wn * 64 + fn * 16 + lr;
#pragma unroll
      for (int j = 0; j < 4; j++) {
        const size_t idx = (size_t)(rb + j) * N + col;
        if constexpr (EPI == 0) {
          ((float*)Cv)[idx] = acc[fm][fn][j];
        } else if constexpr (EPI == 1) {
          ((__hip_bfloat16*)Cv)[idx] = __float2bfloat16(acc[fm][fn][j]);
        } else {
          const float x = __bfloat162float(G[idx]);
          const float tt = tanhf(0.7978845608028654f * (x + 0.044715f * x * x * x));
          ((__hip_bfloat16*)Cv)[idx] = __float2bfloat16(0.5f * x * (1.f + tt) * acc[fm][fn][j]);
        }
      }
    }
  }
}

// ---------------- rope + split + scale: qkv f32 [S][4096] -> Q/K/V bf16 head-major ----------------
__global__ void k_rope_split(const float* __restrict__ qkv, const float* __restrict__ cosb,
                             const float* __restrict__ sinb, __hip_bfloat16* __restrict__ qo,
                             __hip_bfloat16* __restrict__ ko, __hip_bfloat16* __restrict__ vo) {
  const int s = blockIdx.x;
  const float* row = qkv + (size_t)s * QKVN;
  const float* cr = cosb + (size_t)s * 128;
  const float* sr = sinb + (size_t)s * 128;
  for (int idx = threadIdx.x; idx < (NHEAD + NKVH) * 128; idx += 256) {
    const int hh = idx >> 7, d = idx & 127;
    const float cv = cr[d], sv = sr[d];
    if (hh < NHEAD) {
      const float x1 = row[hh * DHEAD + d], x2 = row[hh * DHEAD + 128 + d];
      const size_t base = ((size_t)hh * S_LEN + s) * DHEAD;
      qo[base + d]       = __float2bfloat16((x1 * cv - x2 * sv) * QSCALE);
      qo[base + 128 + d] = __float2bfloat16((x1 * sv + x2 * cv) * QSCALE);
    } else {
      const int kv = hh - NHEAD;
      const float x1 = row[NHEAD * DHEAD + kv * DHEAD + d];
      const float x2 = row[NHEAD * DHEAD + kv * DHEAD + 128 + d];
      const size_t base = ((size_t)kv * S_LEN + s) * DHEAD;
      ko[base + d]       = __float2bfloat16(x1 * cv - x2 * sv);
      ko[base + 128 + d] = __float2bfloat16(x1 * sv + x2 * cv);
    }
  }
  for (int idx = threadIdx.x; idx < NKVH * DHEAD; idx += 256) {
    const int kv = idx >> 8, d = idx & 255;
    vo[((size_t)kv * S_LEN + s) * DHEAD + d] =
        __float2bfloat16(row[NHEAD * DHEAD + NKVH * DHEAD + kv * DHEAD + d]);
  }
}

// ---------------- attention: sliding-window causal, softcap; vector f32 ----------------
// grid (S/16, H), 256 thr. Thread (r = t>>4, c = t&15): row q0+r, d-slices {2c+32j}.
// Softcap bounds scores to [-50,50] -> softmax without max-subtraction is f32-safe.
__global__ __launch_bounds__(256) void k_attn(const __hip_bfloat16* __restrict__ Q,
                                              const __hip_bfloat16* __restrict__ Kb,
                                              const __hip_bfloat16* __restrict__ Vb,
                                              __hip_bfloat16* __restrict__ O) {
  __shared__ float qs[16][258];
  __shared__ alignas(16) __hip_bfloat16 kvs[64][260];
  __shared__ float es[16][65];
  const int h = blockIdx.y, kvh = h >> 1;
  const int q0 = blockIdx.x * 16;
  const int t = threadIdx.x;
  const int r = t >> 4, c = t & 15;

  for (int i = t; i < 16 * 256; i += 256) {
    const int rr = i >> 8, d = i & 255;
    qs[rr][d] = __bfloat162float(Q[((size_t)h * S_LEN + q0 + rr) * DHEAD + d]);
  }
  const int q = q0 + r;
  const int klo = q - WINM1;
  int kc0 = q0 - WINM1;
  if (kc0 < 0) kc0 = 0;
  kc0 &= ~63;

  float out2[8][2];
#pragma unroll
  for (int j = 0; j < 8; j++) { out2[j][0] = 0.f; out2[j][1] = 0.f; }
  float sum = 0.f;
  __syncthreads();

  for (int kc = kc0; kc <= q0 + 15; kc += 64) {
    // stage K chunk (u32 = 2 bf16), coalesced, zero-pad past S
    for (int i = t; i < 64 * 128; i += 256) {
      const int rr = i >> 7, du = i & 127;
      const int krow = kc + rr;
      uint32_t val = 0u;
      if (krow < S_LEN) val = *(const uint32_t*)(Kb + ((size_t)kvh * S_LEN + krow) * DHEAD + du * 2);
      *(uint32_t*)(&kvs[rr][du * 2]) = val;
    }
    __syncthreads();
#pragma unroll
    for (int i = 0; i < 4; i++) {
      const int k = kc + c + 16 * i;
      float e = 0.f;
      if (k >= klo && k <= q) {
        float dot = 0.f;
        const uint32_t* krow = (const uint32_t*)(&kvs[k - kc][0]);
        const float* qrow = &qs[r][0];
#pragma unroll 8
        for (int du = 0; du < 128; du++) {
          const uint32_t pk = krow[du];
          dot += qrow[2 * du] * bf16lo(pk);
          dot += qrow[2 * du + 1] * bf16hi(pk);
        }
        e = __expf(tanhf(dot * (1.0f / CAPF)) * CAPF);
        sum += e;
      }
      es[r][c + 16 * i] = e;
    }
    __syncthreads();  // es done + K reads done before V overwrite
    // stage V chunk
    for (int i = t; i < 64 * 128; i += 256) {
      const int rr = i >> 7, du = i & 127;
      const int krow = kc + rr;
      uint32_t val = 0u;
      if (krow < S_LEN) val = *(const uint32_t*)(Vb + ((size_t)kvh * S_LEN + krow) * DHEAD + du * 2);
      *(uint32_t*)(&kvs[rr][du * 2]) = val;
    }
    __syncthreads();
    for (int kk = 0; kk < 64; kk++) {
      const float e = es[r][kk];
      if (e != 0.f) {
#pragma unroll
        for (int j = 0; j < 8; j++) {
          const uint32_t pv = *(const uint32_t*)(&kvs[kk][32 * j + 2 * c]);
          out2[j][0] += e * bf16lo(pv);
          out2[j][1] += e * bf16hi(pv);
        }
      }
    }
    __syncthreads();  // PV done before next K stage
  }
#pragma unroll
  for (int off = 1; off < 16; off <<= 1) sum += __shfl_xor(sum, off, 64);
  const float inv = 1.f / sum;
  __hip_bfloat16* ob = O + (size_t)q * ODIM + h * DHEAD + 2 * c;
#pragma unroll
  for (int j = 0; j < 8; j++) {
    __hip_bfloat162 pr;
    pr.x = __float2bfloat16(out2[j][0] * inv);
    pr.y = __float2bfloat16(out2[j][1] * inv);
    *reinterpret_cast<__hip_bfloat162*>(ob + 32 * j) = pr;
  }
}

// ---------------- launcher ----------------
extern "C" void kernel_launch(void* const* d_in, const int* in_sizes, int n_in,
                              void* d_out, int out_size, void* d_ws, size_t ws_size,
                              hipStream_t stream) {
  const float* hidden  = (const float*)d_in[0];
  const float* qkv_w   = (const float*)d_in[1];
  const float* o_w     = (const float*)d_in[2];
  const float* gate_w  = (const float*)d_in[3];
  const float* up_w    = (const float*)d_in[4];
  const float* down_w  = (const float*)d_in[5];
  const float* in_ln   = (const float*)d_in[6];
  const float* post_attn_ln = (const float*)d_in[7];
  const float* pre_ffw_ln   = (const float*)d_in[8];
  const float* post_ffw_ln  = (const float*)d_in[9];
  const float* cosb    = (const float*)d_in[10];
  const float* sinb    = (const float*)d_in[11];
  float* out = (float*)d_out;
  char* ws = (char*)d_ws;

  // ---- tight workspace layout (bytes); single reusable weight slot ----
  // W    [0,          42467328)  : current transposed weight bf16 (max 9216x2304)
  // HF   [42467328,   61341696)  : h residual f32 [2048][2304]
  // X    [61341696,   70778880)  : x_norm bf16 [2048][2304] (Xb steps 2-3, X2 steps 8-10)
  // S1   [70778880,  108527616)  : QKV f32 (steps 3-4) -> GATEB bf16 (9-10) -> Yf f32 (11-12)
  // S2   [108527616, 146276352)  : Q/K/V bf16 (4-5) + ATTN bf16 @tail (5-6);
  //                                PROJ f32 @base (6-7); ACT bf16 full (10-11)
  const size_t OFF_W   = 0;
  const size_t OFF_HF  = 42467328;
  const size_t OFF_X   = 61341696;
  const size_t OFF_S1  = 70778880;
  const size_t OFF_S2  = 108527616;
  const size_t NEED    = 146276352;

  if (ws_size < NEED) {  // diagnostic: encode ws MiB into output
    k_fill<<<1024, 256, 0, stream>>>(out, 100000.0f + (float)(ws_size >> 20), (size_t)out_size);
    return;
  }

  __hip_bfloat16* W    = (__hip_bfloat16*)(ws + OFF_W);
  float*          Hf   = (float*)(ws + OFF_HF);
  __hip_bfloat16* Xb   = (__hip_bfloat16*)(ws + OFF_X);
  float*          QKV  = (float*)(ws + OFF_S1);
  __hip_bfloat16* GATEB= (__hip_bfloat16*)(ws + OFF_S1);
  float*          Yf   = (float*)(ws + OFF_S1);
  __hip_bfloat16* Qb   = (__hip_bfloat16*)(ws + OFF_S2);
  __hip_bfloat16* Kb   = (__hip_bfloat16*)(ws + OFF_S2 + 8388608);
  __hip_bfloat16* Vb   = (__hip_bfloat16*)(ws + OFF_S2 + 12582912);
  __hip_bfloat16* ATTN = (__hip_bfloat16*)(ws + OFF_S2 + 29360128);  // tail 8.39MB
  float*          PROJ = (float*)(ws + OFF_S2);
  __hip_bfloat16* ACT  = (__hip_bfloat16*)(ws + OFF_S2);

  // 1. qkv weight -> W ; x = rmsnorm(hidden) -> Xb ; qkv = Xb @ W^T (f32)
  k_transpose_bf16<<<dim3(QKVN / 32, HIDDEN / 32), 256, 0, stream>>>(qkv_w, W, HIDDEN, QKVN);
  k_rmsnorm<false, true><<<S_LEN, 256, 0, stream>>>(hidden, in_ln, nullptr, Xb);
  k_gemm_bt<0><<<dim3(QKVN / 128, S_LEN / 128), 256, 0, stream>>>(Xb, W, QKV, nullptr, QKVN, HIDDEN);
  // 2. rope + split (+fold SCALE into q)
  k_rope_split<<<S_LEN, 256, 0, stream>>>(QKV, cosb, sinb, Qb, Kb, Vb);
  // 3. attention -> ATTN (bf16)
  k_attn<<<dim3(S_LEN / 16, NHEAD), 256, 0, stream>>>(Qb, Kb, Vb, ATTN);
  // 4. o weight -> W ; proj = ATTN @ W^T (f32)
  k_transpose_bf16<<<dim3(HIDDEN / 32, ODIM / 32), 256, 0, stream>>>(o_w, W, ODIM, HIDDEN);
  k_gemm_bt<0><<<dim3(HIDDEN / 128, S_LEN / 128), 256, 0, stream>>>(ATTN, W, PROJ, nullptr, HIDDEN, ODIM);
  // 5. h = hidden + rmsnorm(proj) ; x2 = rmsnorm(h) -> Xb slot
  k_rmsnorm<true, false><<<S_LEN, 256, 0, stream>>>(PROJ, post_attn_ln, hidden, Hf);
  k_rmsnorm<false, true><<<S_LEN, 256, 0, stream>>>(Hf, pre_ffw_ln, nullptr, Xb);
  // 6. gate weight -> W ; gate = X2 @ W^T (bf16)
  k_transpose_bf16<<<dim3(FFDIM / 32, HIDDEN / 32), 256, 0, stream>>>(gate_w, W, HIDDEN, FFDIM);
  k_gemm_bt<1><<<dim3(FFDIM / 128, S_LEN / 128), 256, 0, stream>>>(Xb, W, GATEB, nullptr, FFDIM, HIDDEN);
  // 7. up weight -> W ; act = gelu(gate) * (X2 @ W^T) (bf16, fused epilogue)
  k_transpose_bf16<<<dim3(FFDIM / 32, HIDDEN / 32), 256, 0, stream>>>(up_w, W, HIDDEN, FFDIM);
  k_gemm_bt<2><<<dim3(FFDIM / 128, S_LEN / 128), 256, 0, stream>>>(Xb, W, ACT, GATEB, FFDIM, HIDDEN);
  // 8. down weight -> W ; y = ACT @ W^T (f32)
  k_transpose_bf16<<<dim3(HIDDEN / 32, FFDIM / 32), 256, 0, stream>>>(down_w, W, FFDIM, HIDDEN);
  k_gemm_bt<0><<<dim3(HIDDEN / 128, S_LEN / 128), 256, 0, stream>>>(ACT, W, Yf, nullptr, HIDDEN, FFDIM);
  // 9. out = h + rmsnorm(y)
  k_rmsnorm<true, false><<<S_LEN, 256, 0, stream>>>(Yf, post_ffw_ln, Hf, out);
}

// Round 3
// 941.908 us; speedup vs baseline: 1.9991x; 1.9991x over previous
//
#include <hip/hip_runtime.h>
#include <hip/hip_bf16.h>
#include <cstdint>
#include <cstddef>

// ---------------- constants ----------------
#define S_LEN  2048
#define HIDDEN 2304
#define NHEAD  8
#define NKVH   4
#define DHEAD  256
#define FFDIM  9216
#define QKVN   4096   // (H + 2*KV) * D
#define ODIM   2048   // H * D
#define WINM1  1023
#define QSCALE 0.0625f
#define CAPF   50.0f

typedef __attribute__((ext_vector_type(4))) float f32x4;
typedef __attribute__((ext_vector_type(8))) short s16x8;

// async global->LDS 16B copy; lptr must be wave-uniform, HW adds lane*16
__device__ __forceinline__ void gload_lds16(const void* gptr, void* lptr) {
  __builtin_amdgcn_global_load_lds(
      (const __attribute__((address_space(1))) unsigned int*)gptr,
      (__attribute__((address_space(3))) unsigned int*)lptr, 16, 0, 0);
}

// ---------------- diagnostic fill (ws too small): value encodes ws MiB ----------------
__global__ void k_fill(float* p, float v, size_t n) {
  size_t i = (size_t)blockIdx.x * blockDim.x + threadIdx.x;
  size_t st = (size_t)gridDim.x * blockDim.x;
  for (; i < n; i += st) p[i] = v;
}

// ---------------- f32 [R][C] -> bf16 [C][R] ----------------
__global__ void k_transpose_bf16(const float* __restrict__ in, __hip_bfloat16* __restrict__ out,
                                 int R, int C) {
  __shared__ float tile[32][33];
  const int c0 = blockIdx.x * 32, r0 = blockIdx.y * 32;
  const int tc = threadIdx.x & 31, tr = threadIdx.x >> 5;  // 32 x 8
#pragma unroll
  for (int i = 0; i < 4; i++)
    tile[tr + 8 * i][tc] = in[(size_t)(r0 + tr + 8 * i) * C + c0 + tc];
  __syncthreads();
#pragma unroll
  for (int i = 0; i < 4; i++)
    out[(size_t)(c0 + tr + 8 * i) * R + r0 + tc] = __float2bfloat16(tile[tc][tr + 8 * i]);
}

// ---------------- rmsnorm (row = 2304), optional residual add, f32/bf16 out ----------------
template <bool ADD, bool BF16OUT>
__global__ void k_rmsnorm(const float* __restrict__ x, const float* __restrict__ w,
                          const float* __restrict__ res, void* __restrict__ outv) {
  const int row = blockIdx.x;
  const float* xr = x + (size_t)row * HIDDEN;
  float ss = 0.f;
  for (int i = threadIdx.x; i < HIDDEN; i += 256) { float v = xr[i]; ss += v * v; }
#pragma unroll
  for (int off = 32; off >= 1; off >>= 1) ss += __shfl_down(ss, off);
  __shared__ float red[4];
  __shared__ float srstd;
  if ((threadIdx.x & 63) == 0) red[threadIdx.x >> 6] = ss;
  __syncthreads();
  if (threadIdx.x == 0) {
    float tot = red[0] + red[1] + red[2] + red[3];
    srstd = rsqrtf(tot / (float)HIDDEN + 1e-6f);
  }
  __syncthreads();
  const float rstd = srstd;
  for (int i = threadIdx.x; i < HIDDEN; i += 256) {
    float v = xr[i] * rstd * (1.f + w[i]);
    if constexpr (ADD) v += res[(size_t)row * HIDDEN + i];
    if constexpr (BF16OUT)
      ((__hip_bfloat16*)outv)[(size_t)row * HIDDEN + i] = __float2bfloat16(v);
    else
      ((float*)outv)[(size_t)row * HIDDEN + i] = v;
  }
}

// ---------------- bf16 GEMM: C[M][N] = A[M][K] * Bt[N][K]^T  (m97 structure) ----------------
// EPI: 0 = f32 out; 1 = bf16 out; 2 = bf16 out, val = gelu_tanh(G[r][c]) * acc
template <int EPI>
__global__ __launch_bounds__(256) void k_gemm_bt(const __hip_bfloat16* __restrict__ A,
                                                 const __hip_bfloat16* __restrict__ Bt,
                                                 void* __restrict__ Cv,
                                                 const __hip_bfloat16* __restrict__ G,
                                                 int N, int K) {
  __shared__ alignas(16) __hip_bfloat16 sA[128 * 64];
  __shared__ alignas(16) __hip_bfloat16 sB[128 * 64];
  const int t = threadIdx.x;
  const int w = t >> 6;
  const int wm = w >> 1, wn = w & 1;
  const int m0 = blockIdx.y * 128, n0 = blockIdx.x * 128;
  const int lr = t & 15, lg = (t & 63) >> 4;
  const int srow = t >> 3, sc8 = t & 7;

  f32x4 acc[4][4];
#pragma unroll
  for (int a = 0; a < 4; a++)
#pragma unroll
    for (int b = 0; b < 4; b++) acc[a][b] = (f32x4){0.f, 0.f, 0.f, 0.f};

  for (int kt = 0; kt < K; kt += 64) {
#pragma unroll
    for (int i = 0; i < 4; i++) {
      const __hip_bfloat16* g = A + (size_t)(m0 + i * 32 + srow) * K + kt + sc8 * 8;
      gload_lds16(g, sA + (size_t)(i * 256 + w * 64) * 8);
    }
#pragma unroll
    for (int i = 0; i < 4; i++) {
      const __hip_bfloat16* g = Bt + (size_t)(n0 + i * 32 + srow) * K + kt + sc8 * 8;
      gload_lds16(g, sB + (size_t)(i * 256 + w * 64) * 8);
    }
    __syncthreads();
#pragma unroll
    for (int ks = 0; ks < 2; ks++) {
      s16x8 af[4], bfr[4];
#pragma unroll
      for (int fm = 0; fm < 4; fm++)
        af[fm] = *reinterpret_cast<const s16x8*>(sA + (wm * 64 + fm * 16 + lr) * 64 + ks * 32 + lg * 8);
#pragma unroll
      for (int fn = 0; fn < 4; fn++)
        bfr[fn] = *reinterpret_cast<const s16x8*>(sB + (wn * 64 + fn * 16 + lr) * 64 + ks * 32 + lg * 8);
#pragma unroll
      for (int fm = 0; fm < 4; fm++)
#pragma unroll
        for (int fn = 0; fn < 4; fn++)
          acc[fm][fn] = __builtin_amdgcn_mfma_f32_16x16x32_bf16(af[fm], bfr[fn], acc[fm][fn], 0, 0, 0);
    }
    __syncthreads();
  }
  // C/D layout (m89-verified): col = lane&15, row = (lane>>4)*4 + reg
#pragma unroll
  for (int fm = 0; fm < 4; fm++) {
    const int rb = m0 + wm * 64 + fm * 16 + lg * 4;
#pragma unroll
    for (int fn = 0; fn < 4; fn++) {
      const int col = n0 + wn * 64 + fn * 16 + lr;
#pragma unroll
      for (int j = 0; j < 4; j++) {
        const size_t idx = (size_t)(rb + j) * N + col;
        if constexpr (EPI == 0) {
          ((float*)Cv)[idx] = acc[fm][fn][j];
        } else if constexpr (EPI == 1) {
          ((__hip_bfloat16*)Cv)[idx] = __float2bfloat16(acc[fm][fn][j]);
        } else {
          const float x = __bfloat162float(G[idx]);
          const float tt = tanhf(0.7978845608028654f * (x + 0.044715f * x * x * x));
          ((__hip_bfloat16*)Cv)[idx] = __float2bfloat16(0.5f * x * (1.f + tt) * acc[fm][fn][j]);
        }
      }
    }
  }
}

// ---------------- rope + split + scale: qkv f32 [S][4096] -> Q/K bf16 head-major ----------------
__global__ void k_rope_split(const float* __restrict__ qkv, const float* __restrict__ cosb,
                             const float* __restrict__ sinb, __hip_bfloat16* __restrict__ qo,
                             __hip_bfloat16* __restrict__ ko) {
  const int s = blockIdx.x;
  const float* row = qkv + (size_t)s * QKVN;
  const float* cr = cosb + (size_t)s * 128;
  const float* sr = sinb + (size_t)s * 128;
  for (int idx = threadIdx.x; idx < (NHEAD + NKVH) * 128; idx += 256) {
    const int hh = idx >> 7, d = idx & 127;
    const float cv = cr[d], sv = sr[d];
    if (hh < NHEAD) {
      const float x1 = row[hh * DHEAD + d], x2 = row[hh * DHEAD + 128 + d];
      const size_t base = ((size_t)hh * S_LEN + s) * DHEAD;
      qo[base + d]       = __float2bfloat16((x1 * cv - x2 * sv) * QSCALE);
      qo[base + 128 + d] = __float2bfloat16((x1 * sv + x2 * cv) * QSCALE);
    } else {
      const int kv = hh - NHEAD;
      const float x1 = row[NHEAD * DHEAD + kv * DHEAD + d];
      const float x2 = row[NHEAD * DHEAD + kv * DHEAD + 128 + d];
      const size_t base = ((size_t)kv * S_LEN + s) * DHEAD;
      ko[base + d]       = __float2bfloat16(x1 * cv - x2 * sv);
      ko[base + 128 + d] = __float2bfloat16(x1 * sv + x2 * cv);
    }
  }
}

// ---------------- V extract + transpose: qkv f32 -> Vt[kv][256 d][2048 s] bf16 ----------------
__global__ __launch_bounds__(256) void k_vsplit_t(const float* __restrict__ qkv,
                                                  __hip_bfloat16* __restrict__ vt) {
  __shared__ float tile[64][260];  // 64 s-rows x 256 d (pad 260 for aligned float4 writes)
  const int s0 = blockIdx.x * 64, kv = blockIdx.y;
  const int t = threadIdx.x;
  const int rr = t >> 6, c4 = t & 63;  // 4 rows x 64 float4-cols per pass
#pragma unroll
  for (int p = 0; p < 16; p++) {
    const int row = rr + p * 4;
    const float4 v = *(const float4*)(qkv + (size_t)(s0 + row) * QKVN + (NHEAD + NKVH) * DHEAD +
                                      kv * DHEAD + c4 * 4);
    *(float4*)(&tile[row][c4 * 4]) = v;
  }
  __syncthreads();
  const int c = t & 31, dr = t >> 5;  // s-pair 2c, 8 d-rows per pass
#pragma unroll
  for (int p = 0; p < 32; p++) {
    const int d = dr + p * 8;
    __hip_bfloat162 pr;
    pr.x = __float2bfloat16(tile[2 * c][d]);
    pr.y = __float2bfloat16(tile[2 * c + 1][d]);
    *(__hip_bfloat162*)(vt + ((size_t)kv * DHEAD + d) * S_LEN + s0 + 2 * c) = pr;
  }
}

// ---------------- MFMA flash attention: sliding-window causal + softcap ----------------
// grid (S/64, H), 256 thr = 4 waves; wave wq owns q-rows [q0+16wq, q0+16wq+16).
// Softcap bounds scores to [-50,50] -> unnormalized exp accumulation is f32-safe (no rescale).
__global__ __launch_bounds__(256) void k_attn_mfma(const __hip_bfloat16* __restrict__ Q,
                                                   const __hip_bfloat16* __restrict__ Kb,
                                                   const __hip_bfloat16* __restrict__ Vt,
                                                   __hip_bfloat16* __restrict__ O) {
  __shared__ alignas(16) __hip_bfloat16 Ks[64 * 264];   // K tile, pad 264 (132 dw: uniform banks)
  __shared__ alignas(16) __hip_bfloat16 Vs[256 * 72];   // V^T tile, pad 72 (36 dw)
  __shared__ alignas(16) __hip_bfloat16 Ps[64 * 72];    // P, per-wave 16-row slices
  const int h = blockIdx.y, kvh = h >> 1;
  const int q0 = blockIdx.x * 64;
  const int t = threadIdx.x;
  const int wq = t >> 6;
  const int l = t & 63;
  const int lr = l & 15, lg = l >> 4;

  // Q fragments in registers (A-frag: row = lane&15, k = ks*32 + lg*8 + e)
  s16x8 qf[8];
  {
    const __hip_bfloat16* qrow = Q + ((size_t)h * S_LEN + q0 + wq * 16 + lr) * DHEAD;
#pragma unroll
    for (int ks = 0; ks < 8; ks++) qf[ks] = *(const s16x8*)(qrow + ks * 32 + lg * 8);
  }
  f32x4 acc[16];
#pragma unroll
  for (int i = 0; i < 16; i++) acc[i] = (f32x4){0.f, 0.f, 0.f, 0.f};
  float rsum[4] = {0.f, 0.f, 0.f, 0.f};

  int lo = q0 - WINM1;
  if (lo < 0) lo = 0;
  lo &= ~63;
  const int qrow_base = q0 + wq * 16 + lg * 4;  // +j = this lane's C/D rows

  for (int kc = lo; kc <= q0; kc += 64) {
    // stage K tile [64][256] -> Ks (rows always < S by construction)
#pragma unroll
    for (int p = 0; p < 8; p++) {
      const int idx = t + p * 256;
      const int row = idx >> 5, c16 = idx & 31;
      s16x8 v = *(const s16x8*)(Kb + ((size_t)kvh * S_LEN + kc + row) * DHEAD + c16 * 8);
      *(s16x8*)(Ks + row * 264 + c16 * 8) = v;
    }
    // stage V^T tile [256 d][64 k] -> Vs
#pragma unroll
    for (int p = 0; p < 8; p++) {
      const int idx = t + p * 256;
      const int d = idx >> 3, ch = idx & 7;
      s16x8 v = *(const s16x8*)(Vt + ((size_t)kvh * DHEAD + d) * S_LEN + kc + ch * 8);
      *(s16x8*)(Vs + d * 72 + ch * 8) = v;
    }
    __syncthreads();

    // QK^T: 4 col-frags x 8 k-steps
    f32x4 sc[4];
#pragma unroll
    for (int f = 0; f < 4; f++) {
      sc[f] = (f32x4){0.f, 0.f, 0.f, 0.f};
#pragma unroll
      for (int ks = 0; ks < 8; ks++) {
        s16x8 bf = *(const s16x8*)(Ks + (f * 16 + lr) * 264 + ks * 32 + lg * 8);
        sc[f] = __builtin_amdgcn_mfma_f32_16x16x32_bf16(qf[ks], bf, sc[f], 0, 0, 0);
      }
    }
    // softcap + mask + exp; write P (bf16) to per-wave LDS slice
#pragma unroll
    for (int f = 0; f < 4; f++) {
      const int k = kc + f * 16 + lr;
#pragma unroll
      for (int j = 0; j < 4; j++) {
        const int q = qrow_base + j;
        float p = 0.f;
        if (k <= q && q - k <= WINM1) {
          const float s = sc[f][j];
          const float u = exp2f(s * 0.057707801635558534f);          // e^(2s/50)
          const float arg = 72.134752044448169f -
                            144.26950408889634f * __builtin_amdgcn_rcpf(u + 1.f);
          p = exp2f(arg);                                            // e^(50*tanh(s/50))
        }
        const __hip_bfloat16 pb = __float2bfloat16(p);
        Ps[(wq * 16 + lg * 4 + j) * 72 + f * 16 + lr] = pb;
        rsum[j] += __bfloat162float(pb);
      }
    }
    // PV: A = P (16xk), B = V^T rows (d x k); 16 d-frags x 2 k-steps
#pragma unroll
    for (int ks2 = 0; ks2 < 2; ks2++) {
      s16x8 pa = *(const s16x8*)(Ps + (wq * 16 + lr) * 72 + ks2 * 32 + lg * 8);
#pragma unroll
      for (int f2 = 0; f2 < 16; f2++) {
        s16x8 vb = *(const s16x8*)(Vs + (f2 * 16 + lr) * 72 + ks2 * 32 + lg * 8);
        acc[f2] = __builtin_amdgcn_mfma_f32_16x16x32_bf16(pa, vb, acc[f2], 0, 0, 0);
      }
    }
    __syncthreads();  // all waves done reading before next stage overwrites
  }
  // row sums: reduce across the 16 lanes of each group (rows match C/D ownership)
#pragma unroll
  for (int j = 0; j < 4; j++) {
    float s = rsum[j];
#pragma unroll
    for (int off = 1; off < 16; off <<= 1) s += __shfl_xor(s, off, 64);
    rsum[j] = 1.f / s;
  }
#pragma unroll
  for (int f2 = 0; f2 < 16; f2++)
#pragma unroll
    for (int j = 0; j < 4; j++)
      O[(size_t)(qrow_base + j) * ODIM + h * DHEAD + f2 * 16 + lr] =
          __float2bfloat16(acc[f2][j] * rsum[j]);
}

// ---------------- launcher ----------------
extern "C" void kernel_launch(void* const* d_in, const int* in_sizes, int n_in,
                              void* d_out, int out_size, void* d_ws, size_t ws_size,
                              hipStream_t stream) {
  const float* hidden  = (const float*)d_in[0];
  const float* qkv_w   = (const float*)d_in[1];
  const float* o_w     = (const float*)d_in[2];
  const float* gate_w  = (const float*)d_in[3];
  const float* up_w    = (const float*)d_in[4];
  const float* down_w  = (const float*)d_in[5];
  const float* in_ln   = (const float*)d_in[6];
  const float* post_attn_ln = (const float*)d_in[7];
  const float* pre_ffw_ln   = (const float*)d_in[8];
  const float* post_ffw_ln  = (const float*)d_in[9];
  const float* cosb    = (const float*)d_in[10];
  const float* sinb    = (const float*)d_in[11];
  float* out = (float*)d_out;
  char* ws = (char*)d_ws;

  // ---- workspace layout (bytes); single reusable weight slot ----
  const size_t OFF_W   = 0;
  const size_t OFF_HF  = 42467328;
  const size_t OFF_X   = 61341696;
  const size_t OFF_S1  = 70778880;
  const size_t OFF_S2  = 108527616;
  const size_t NEED    = 146276352;

  if (ws_size < NEED) {  // diagnostic: encode ws MiB into output
    k_fill<<<1024, 256, 0, stream>>>(out, 100000.0f + (float)(ws_size >> 20), (size_t)out_size);
    return;
  }

  __hip_bfloat16* W    = (__hip_bfloat16*)(ws + OFF_W);
  float*          Hf   = (float*)(ws + OFF_HF);
  __hip_bfloat16* Xb   = (__hip_bfloat16*)(ws + OFF_X);
  float*          QKV  = (float*)(ws + OFF_S1);
  __hip_bfloat16* GATEB= (__hip_bfloat16*)(ws + OFF_S1);
  float*          Yf   = (float*)(ws + OFF_S1);
  __hip_bfloat16* Qb   = (__hip_bfloat16*)(ws + OFF_S2);
  __hip_bfloat16* Kb   = (__hip_bfloat16*)(ws + OFF_S2 + 8388608);
  __hip_bfloat16* Vtb  = (__hip_bfloat16*)(ws + OFF_S2 + 12582912);  // [4][256][2048] bf16
  __hip_bfloat16* ATTN = (__hip_bfloat16*)(ws + OFF_S2 + 29360128);  // tail 8.39MB
  float*          PROJ = (float*)(ws + OFF_S2);
  __hip_bfloat16* ACT  = (__hip_bfloat16*)(ws + OFF_S2);

  // 1. qkv weight -> W ; x = rmsnorm(hidden) -> Xb ; qkv = Xb @ W^T (f32)
  k_transpose_bf16<<<dim3(QKVN / 32, HIDDEN / 32), 256, 0, stream>>>(qkv_w, W, HIDDEN, QKVN);
  k_rmsnorm<false, true><<<S_LEN, 256, 0, stream>>>(hidden, in_ln, nullptr, Xb);
  k_gemm_bt<0><<<dim3(QKVN / 128, S_LEN / 128), 256, 0, stream>>>(Xb, W, QKV, nullptr, QKVN, HIDDEN);
  // 2. rope+split Q/K ; V extract+transpose
  k_rope_split<<<S_LEN, 256, 0, stream>>>(QKV, cosb, sinb, Qb, Kb);
  k_vsplit_t<<<dim3(S_LEN / 64, NKVH), 256, 0, stream>>>(QKV, Vtb);
  // 3. attention -> ATTN (bf16)
  k_attn_mfma<<<dim3(S_LEN / 64, NHEAD), 256, 0, stream>>>(Qb, Kb, Vtb, ATTN);
  // 4. o weight -> W ; proj = ATTN @ W^T (f32)
  k_transpose_bf16<<<dim3(HIDDEN / 32, ODIM / 32), 256, 0, stream>>>(o_w, W, ODIM, HIDDEN);
  k_gemm_bt<0><<<dim3(HIDDEN / 128, S_LEN / 128), 256, 0, stream>>>(ATTN, W, PROJ, nullptr, HIDDEN, ODIM);
  // 5. h = hidden + rmsnorm(proj) ; x2 = rmsnorm(h) -> Xb slot
  k_rmsnorm<true, false><<<S_LEN, 256, 0, stream>>>(PROJ, post_attn_ln, hidden, Hf);
  k_rmsnorm<false, true><<<S_LEN, 256, 0, stream>>>(Hf, pre_ffw_ln, nullptr, Xb);
  // 6. gate weight -> W ; gate = X2 @ W^T (bf16)
  k_transpose_bf16<<<dim3(FFDIM / 32, HIDDEN / 32), 256, 0, stream>>>(gate_w, W, HIDDEN, FFDIM);
  k_gemm_bt<1><<<dim3(FFDIM / 128, S_LEN / 128), 256, 0, stream>>>(Xb, W, GATEB, nullptr, FFDIM, HIDDEN);
  // 7. up weight -> W ; act = gelu(gate) * (X2 @ W^T) (bf16, fused epilogue)
  k_transpose_bf16<<<dim3(FFDIM / 32, HIDDEN / 32), 256, 0, stream>>>(up_w, W, HIDDEN, FFDIM);
  k_gemm_bt<2><<<dim3(FFDIM / 128, S_LEN / 128), 256, 0, stream>>>(Xb, W, ACT, GATEB, FFDIM, HIDDEN);
  // 8. down weight -> W ; y = ACT @ W^T (f32)
  k_transpose_bf16<<<dim3(HIDDEN / 32, FFDIM / 32), 256, 0, stream>>>(down_w, W, FFDIM, HIDDEN);
  k_gemm_bt<0><<<dim3(HIDDEN / 128, S_LEN / 128), 256, 0, stream>>>(ACT, W, Yf, nullptr, HIDDEN, FFDIM);
  // 9. out = h + rmsnorm(y)
  k_rmsnorm<true, false><<<S_LEN, 256, 0, stream>>>(Yf, post_ffw_ln, Hf, out);
}

// Round 4
// 914.928 us; speedup vs baseline: 2.0581x; 1.0295x over previous
//
#include <hip/hip_runtime.h>
#include <hip/hip_bf16.h>
#include <cstdint>
#include <cstddef>

// ---------------- constants ----------------
#define S_LEN  2048
#define HIDDEN 2304
#define NHEAD  8
#define NKVH   4
#define DHEAD  256
#define FFDIM  9216
#define QKVN   4096   // (H + 2*KV) * D
#define ODIM   2048   // H * D
#define WINM1  1023
#define QSCALE 0.0625f
#define CAPF   50.0f

typedef __attribute__((ext_vector_type(4))) float f32x4;
typedef __attribute__((ext_vector_type(8))) short s16x8;

// async global->LDS 16B copy; lptr must be wave-uniform, HW adds lane*16
__device__ __forceinline__ void gload_lds16(const void* gptr, void* lptr) {
  __builtin_amdgcn_global_load_lds(
      (const __attribute__((address_space(1))) unsigned int*)gptr,
      (__attribute__((address_space(3))) unsigned int*)lptr, 16, 0, 0);
}

// ---------------- diagnostic fill (ws too small): value encodes ws MiB ----------------
__global__ void k_fill(float* p, float v, size_t n) {
  size_t i = (size_t)blockIdx.x * blockDim.x + threadIdx.x;
  size_t st = (size_t)gridDim.x * blockDim.x;
  for (; i < n; i += st) p[i] = v;
}

// ---------------- f32 [R][C] -> bf16 [C][R] ----------------
__global__ void k_transpose_bf16(const float* __restrict__ in, __hip_bfloat16* __restrict__ out,
                                 int R, int C) {
  __shared__ float tile[32][33];
  const int c0 = blockIdx.x * 32, r0 = blockIdx.y * 32;
  const int tc = threadIdx.x & 31, tr = threadIdx.x >> 5;  // 32 x 8
#pragma unroll
  for (int i = 0; i < 4; i++)
    tile[tr + 8 * i][tc] = in[(size_t)(r0 + tr + 8 * i) * C + c0 + tc];
  __syncthreads();
#pragma unroll
  for (int i = 0; i < 4; i++)
    out[(size_t)(c0 + tr + 8 * i) * R + r0 + tc] = __float2bfloat16(tile[tc][tr + 8 * i]);
}

// ---------------- rmsnorm (row = 2304), optional residual add, f32/bf16 out ----------------
template <bool ADD, bool BF16OUT>
__global__ void k_rmsnorm(const float* __restrict__ x, const float* __restrict__ w,
                          const float* __restrict__ res, void* __restrict__ outv) {
  const int row = blockIdx.x;
  const float* xr = x + (size_t)row * HIDDEN;
  float ss = 0.f;
  for (int i = threadIdx.x; i < HIDDEN; i += 256) { float v = xr[i]; ss += v * v; }
#pragma unroll
  for (int off = 32; off >= 1; off >>= 1) ss += __shfl_down(ss, off);
  __shared__ float red[4];
  __shared__ float srstd;
  if ((threadIdx.x & 63) == 0) red[threadIdx.x >> 6] = ss;
  __syncthreads();
  if (threadIdx.x == 0) {
    float tot = red[0] + red[1] + red[2] + red[3];
    srstd = rsqrtf(tot / (float)HIDDEN + 1e-6f);
  }
  __syncthreads();
  const float rstd = srstd;
  for (int i = threadIdx.x; i < HIDDEN; i += 256) {
    float v = xr[i] * rstd * (1.f + w[i]);
    if constexpr (ADD) v += res[(size_t)row * HIDDEN + i];
    if constexpr (BF16OUT)
      ((__hip_bfloat16*)outv)[(size_t)row * HIDDEN + i] = __float2bfloat16(v);
    else
      ((float*)outv)[(size_t)row * HIDDEN + i] = v;
  }
}

// ---------------- bf16 GEMM (m97 structure): C[M][N] = A[M][K] * Bt[N][K]^T ----------------
// EPI: 0 = f32 out; 1 = bf16 out; 2 = bf16 out, val = gelu_tanh(G[r][c]) * acc
template <int EPI>
__global__ __launch_bounds__(256) void k_gemm_bt(const __hip_bfloat16* __restrict__ A,
                                                 const __hip_bfloat16* __restrict__ Bt,
                                                 void* __restrict__ Cv,
                                                 const __hip_bfloat16* __restrict__ G,
                                                 int N, int K) {
  __shared__ alignas(16) __hip_bfloat16 sA[128 * 64];
  __shared__ alignas(16) __hip_bfloat16 sB[128 * 64];
  const int t = threadIdx.x;
  const int w = t >> 6;
  const int wm = w >> 1, wn = w & 1;
  const int m0 = blockIdx.y * 128, n0 = blockIdx.x * 128;
  const int lr = t & 15, lg = (t & 63) >> 4;
  const int srow = t >> 3, sc8 = t & 7;

  f32x4 acc[4][4];
#pragma unroll
  for (int a = 0; a < 4; a++)
#pragma unroll
    for (int b = 0; b < 4; b++) acc[a][b] = (f32x4){0.f, 0.f, 0.f, 0.f};

  for (int kt = 0; kt < K; kt += 64) {
#pragma unroll
    for (int i = 0; i < 4; i++) {
      const __hip_bfloat16* g = A + (size_t)(m0 + i * 32 + srow) * K + kt + sc8 * 8;
      gload_lds16(g, sA + (size_t)(i * 256 + w * 64) * 8);
    }
#pragma unroll
    for (int i = 0; i < 4; i++) {
      const __hip_bfloat16* g = Bt + (size_t)(n0 + i * 32 + srow) * K + kt + sc8 * 8;
      gload_lds16(g, sB + (size_t)(i * 256 + w * 64) * 8);
    }
    __syncthreads();
#pragma unroll
    for (int ks = 0; ks < 2; ks++) {
      s16x8 af[4], bfr[4];
#pragma unroll
      for (int fm = 0; fm < 4; fm++)
        af[fm] = *reinterpret_cast<const s16x8*>(sA + (wm * 64 + fm * 16 + lr) * 64 + ks * 32 + lg * 8);
#pragma unroll
      for (int fn = 0; fn < 4; fn++)
        bfr[fn] = *reinterpret_cast<const s16x8*>(sB + (wn * 64 + fn * 16 + lr) * 64 + ks * 32 + lg * 8);
#pragma unroll
      for (int fm = 0; fm < 4; fm++)
#pragma unroll
        for (int fn = 0; fn < 4; fn++)
          acc[fm][fn] = __builtin_amdgcn_mfma_f32_16x16x32_bf16(af[fm], bfr[fn], acc[fm][fn], 0, 0, 0);
    }
    __syncthreads();
  }
  // C/D layout (m89-verified): col = lane&15, row = (lane>>4)*4 + reg
#pragma unroll
  for (int fm = 0; fm < 4; fm++) {
    const int rb = m0 + wm * 64 + fm * 16 + lg * 4;
#pragma unroll
    for (int fn = 0; fn < 4; fn++) {
      const int col = n0 + wn * 64 + fn * 16 + lr;
#pragma unroll
      for (int j = 0; j < 4; j++) {
        const size_t idx = (size_t)(rb + j) * N + col;
        if constexpr (EPI == 0) {
          ((float*)Cv)[idx] = acc[fm][fn][j];
        } else if constexpr (EPI == 1) {
          ((__hip_bfloat16*)Cv)[idx] = __float2bfloat16(acc[fm][fn][j]);
        } else {
          const float x = __bfloat162float(G[idx]);
          const float tt = tanhf(0.7978845608028654f * (x + 0.044715f * x * x * x));
          ((__hip_bfloat16*)Cv)[idx] = __float2bfloat16(0.5f * x * (1.f + tt) * acc[fm][fn][j]);
        }
      }
    }
  }
}

// ------- pipelined bf16 GEMM: 256x256 tile, BK=32, depth-3 prefetch, counted vmcnt -------
// 512 thr = 8 waves (2M x 4N); wave tile 128x64 = 8x4 frags. LDS: 4 bufs x (A 16K + B 16K).
// Iter t: stage tile t+3 -> buf[(t+3)&3]; ds_read+MFMA tile t from buf[t&3];
//         s_waitcnt vmcnt(8) lgkmcnt(0); s_barrier.   (tile t+1 landed; t+2,t+3 in flight)
// LDS conflict fix: linear dest + inverse-swizzled global source + XOR on read:
//   slot kg holds k-block kg ^ ((row>>1)&3)  -> ds_read_b128 is 2-way (free).
// EPI: 1 = bf16 out; 2 = bf16 out, val = gelu_tanh(G[r][c]) * acc
template <int EPI>
__global__ __launch_bounds__(512, 2) void k_gemm_p(const __hip_bfloat16* __restrict__ A,
                                                   const __hip_bfloat16* __restrict__ Bt,
                                                   void* __restrict__ Cv,
                                                   const __hip_bfloat16* __restrict__ G,
                                                   int N, int K) {
  __shared__ alignas(16) __hip_bfloat16 smem[4 * 16384];  // 128 KiB
  const int t = threadIdx.x;
  const int w = t >> 6;                 // wave 0..7
  const int wm = w >> 2, wn = w & 3;    // 2M x 4N
  const int l = t & 63;
  const int lr = l & 15, lg = l >> 4;

  // bijective XCD swizzle (m204), by-fastest decomposition for B-panel reuse per XCD
  const int nwg = gridDim.x * gridDim.y;
  const int f = blockIdx.y * gridDim.x + blockIdx.x;
  const int q = nwg >> 3, r = nwg & 7;
  const int xcd = f & 7, idx = f >> 3;
  const int swz = (xcd < r ? xcd * (q + 1) : r * (q + 1) + (xcd - r) * q) + idx;
  const int by = swz % gridDim.y, bx = swz / gridDim.y;
  const int m0 = by * 256, n0 = bx * 256;

  const int NT = K >> 5;
  const int srow_base = (l >> 2);          // staging row within 16-row chunk
  const int skg = l & 3;                   // staging k-slot
  const int kgp = (lg ^ ((lr >> 1) & 3)) * 8;  // read-side swizzled k-offset (elements)

  f32x4 acc[8][4];
#pragma unroll
  for (int a = 0; a < 8; a++)
#pragma unroll
    for (int b = 0; b < 4; b++) acc[a][b] = (f32x4){0.f, 0.f, 0.f, 0.f};

  auto stage = [&](int tt, int bufi) {
    const int kt = tt * 32;
    __hip_bfloat16* lbase = smem + bufi * 16384;
#pragma unroll
    for (int j = 0; j < 2; ++j) {
      const int row = (w * 2 + j) * 16 + srow_base;
      const int kgd = skg ^ ((row >> 1) & 3);
      gload_lds16(A + (size_t)(m0 + row) * K + kt + kgd * 8, lbase + (w * 2 + j) * 512);
    }
#pragma unroll
    for (int j = 0; j < 2; ++j) {
      const int row = (w * 2 + j) * 16 + srow_base;
      const int kgd = skg ^ ((row >> 1) & 3);
      gload_lds16(Bt + (size_t)(n0 + row) * K + kt + kgd * 8, lbase + 8192 + (w * 2 + j) * 512);
    }
  };

  // prologue: stage tiles 0,1,2 ; wait tile 0 (8 = tiles 1,2 in flight)
  stage(0, 0);
  stage(1, 1);
  stage(2, 2);
  asm volatile("s_waitcnt vmcnt(8)" ::: "memory");
  __builtin_amdgcn_s_barrier();

  for (int tt = 0; tt < NT; ++tt) {
    const int cur = tt & 3;
    if (tt + 3 < NT) stage(tt + 3, (tt + 3) & 3);

    const __hip_bfloat16* bufA = smem + cur * 16384;
    const __hip_bfloat16* bufB = bufA + 8192;
    s16x8 af[8], bf[4];
#pragma unroll
    for (int fm = 0; fm < 8; fm++)
      af[fm] = *reinterpret_cast<const s16x8*>(bufA + (wm * 128 + fm * 16 + lr) * 32 + kgp);
#pragma unroll
    for (int fn = 0; fn < 4; fn++)
      bf[fn] = *reinterpret_cast<const s16x8*>(bufB + (wn * 64 + fn * 16 + lr) * 32 + kgp);

    __builtin_amdgcn_s_setprio(1);
#pragma unroll
    for (int fm = 0; fm < 8; fm++)
#pragma unroll
      for (int fn = 0; fn < 4; fn++)
        acc[fm][fn] = __builtin_amdgcn_mfma_f32_16x16x32_bf16(af[fm], bf[fn], acc[fm][fn], 0, 0, 0);
    __builtin_amdgcn_s_setprio(0);

    if (tt + 1 < NT) {
      if (tt + 3 < NT)      asm volatile("s_waitcnt vmcnt(8) lgkmcnt(0)" ::: "memory");
      else if (tt + 2 < NT) asm volatile("s_waitcnt vmcnt(4) lgkmcnt(0)" ::: "memory");
      else                  asm volatile("s_waitcnt vmcnt(0) lgkmcnt(0)" ::: "memory");
      __builtin_amdgcn_s_barrier();
    }
  }

  // epilogue: C/D layout col = lane&15, row = (lane>>4)*4 + reg
#pragma unroll
  for (int fm = 0; fm < 8; fm++) {
    const int rb = m0 + wm * 128 + fm * 16 + lg * 4;
#pragma unroll
    for (int fn = 0; fn < 4; fn++) {
      const int col = n0 + wn * 64 + fn * 16 + lr;
#pragma unroll
      for (int j = 0; j < 4; j++) {
        const size_t idxo = (size_t)(rb + j) * N + col;
        if constexpr (EPI == 1) {
          ((__hip_bfloat16*)Cv)[idxo] = __float2bfloat16(acc[fm][fn][j]);
        } else {
          const float x = __bfloat162float(G[idxo]);
          const float tg = tanhf(0.7978845608028654f * (x + 0.044715f * x * x * x));
          ((__hip_bfloat16*)Cv)[idxo] = __float2bfloat16(0.5f * x * (1.f + tg) * acc[fm][fn][j]);
        }
      }
    }
  }
}

// ---------------- rope + split + scale: qkv f32 [S][4096] -> Q/K bf16 head-major ----------------
__global__ void k_rope_split(const float* __restrict__ qkv, const float* __restrict__ cosb,
                             const float* __restrict__ sinb, __hip_bfloat16* __restrict__ qo,
                             __hip_bfloat16* __restrict__ ko) {
  const int s = blockIdx.x;
  const float* row = qkv + (size_t)s * QKVN;
  const float* cr = cosb + (size_t)s * 128;
  const float* sr = sinb + (size_t)s * 128;
  for (int idx = threadIdx.x; idx < (NHEAD + NKVH) * 128; idx += 256) {
    const int hh = idx >> 7, d = idx & 127;
    const float cv = cr[d], sv = sr[d];
    if (hh < NHEAD) {
      const float x1 = row[hh * DHEAD + d], x2 = row[hh * DHEAD + 128 + d];
      const size_t base = ((size_t)hh * S_LEN + s) * DHEAD;
      qo[base + d]       = __float2bfloat16((x1 * cv - x2 * sv) * QSCALE);
      qo[base + 128 + d] = __float2bfloat16((x1 * sv + x2 * cv) * QSCALE);
    } else {
      const int kv = hh - NHEAD;
      const float x1 = row[NHEAD * DHEAD + kv * DHEAD + d];
      const float x2 = row[NHEAD * DHEAD + kv * DHEAD + 128 + d];
      const size_t base = ((size_t)kv * S_LEN + s) * DHEAD;
      ko[base + d]       = __float2bfloat16(x1 * cv - x2 * sv);
      ko[base + 128 + d] = __float2bfloat16(x1 * sv + x2 * cv);
    }
  }
}

// ---------------- V extract + transpose: qkv f32 -> Vt[kv][256 d][2048 s] bf16 ----------------
__global__ __launch_bounds__(256) void k_vsplit_t(const float* __restrict__ qkv,
                                                  __hip_bfloat16* __restrict__ vt) {
  __shared__ float tile[64][260];
  const int s0 = blockIdx.x * 64, kv = blockIdx.y;
  const int t = threadIdx.x;
  const int rr = t >> 6, c4 = t & 63;
#pragma unroll
  for (int p = 0; p < 16; p++) {
    const int row = rr + p * 4;
    const float4 v = *(const float4*)(qkv + (size_t)(s0 + row) * QKVN + (NHEAD + NKVH) * DHEAD +
                                      kv * DHEAD + c4 * 4);
    *(float4*)(&tile[row][c4 * 4]) = v;
  }
  __syncthreads();
  const int c = t & 31, dr = t >> 5;
#pragma unroll
  for (int p = 0; p < 32; p++) {
    const int d = dr + p * 8;
    __hip_bfloat162 pr;
    pr.x = __float2bfloat16(tile[2 * c][d]);
    pr.y = __float2bfloat16(tile[2 * c + 1][d]);
    *(__hip_bfloat162*)(vt + ((size_t)kv * DHEAD + d) * S_LEN + s0 + 2 * c) = pr;
  }
}

// ---------------- MFMA flash attention: sliding-window causal + softcap ----------------
__global__ __launch_bounds__(256) void k_attn_mfma(const __hip_bfloat16* __restrict__ Q,
                                                   const __hip_bfloat16* __restrict__ Kb,
                                                   const __hip_bfloat16* __restrict__ Vt,
                                                   __hip_bfloat16* __restrict__ O) {
  __shared__ alignas(16) __hip_bfloat16 Ks[64 * 264];
  __shared__ alignas(16) __hip_bfloat16 Vs[256 * 72];
  __shared__ alignas(16) __hip_bfloat16 Ps[64 * 72];
  const int h = blockIdx.y, kvh = h >> 1;
  const int q0 = blockIdx.x * 64;
  const int t = threadIdx.x;
  const int wq = t >> 6;
  const int l = t & 63;
  const int lr = l & 15, lg = l >> 4;

  s16x8 qf[8];
  {
    const __hip_bfloat16* qrow = Q + ((size_t)h * S_LEN + q0 + wq * 16 + lr) * DHEAD;
#pragma unroll
    for (int ks = 0; ks < 8; ks++) qf[ks] = *(const s16x8*)(qrow + ks * 32 + lg * 8);
  }
  f32x4 acc[16];
#pragma unroll
  for (int i = 0; i < 16; i++) acc[i] = (f32x4){0.f, 0.f, 0.f, 0.f};
  float rsum[4] = {0.f, 0.f, 0.f, 0.f};

  int lo = q0 - WINM1;
  if (lo < 0) lo = 0;
  lo &= ~63;
  const int qrow_base = q0 + wq * 16 + lg * 4;

  for (int kc = lo; kc <= q0; kc += 64) {
#pragma unroll
    for (int p = 0; p < 8; p++) {
      const int idx = t + p * 256;
      const int row = idx >> 5, c16 = idx & 31;
      s16x8 v = *(const s16x8*)(Kb + ((size_t)kvh * S_LEN + kc + row) * DHEAD + c16 * 8);
      *(s16x8*)(Ks + row * 264 + c16 * 8) = v;
    }
#pragma unroll
    for (int p = 0; p < 8; p++) {
      const int idx = t + p * 256;
      const int d = idx >> 3, ch = idx & 7;
      s16x8 v = *(const s16x8*)(Vt + ((size_t)kvh * DHEAD + d) * S_LEN + kc + ch * 8);
      *(s16x8*)(Vs + d * 72 + ch * 8) = v;
    }
    __syncthreads();

    f32x4 sc[4];
#pragma unroll
    for (int fq = 0; fq < 4; fq++) {
      sc[fq] = (f32x4){0.f, 0.f, 0.f, 0.f};
#pragma unroll
      for (int ks = 0; ks < 8; ks++) {
        s16x8 bfr = *(const s16x8*)(Ks + (fq * 16 + lr) * 264 + ks * 32 + lg * 8);
        sc[fq] = __builtin_amdgcn_mfma_f32_16x16x32_bf16(qf[ks], bfr, sc[fq], 0, 0, 0);
      }
    }
#pragma unroll
    for (int fq = 0; fq < 4; fq++) {
      const int k = kc + fq * 16 + lr;
#pragma unroll
      for (int j = 0; j < 4; j++) {
        const int qq = qrow_base + j;
        float p = 0.f;
        if (k <= qq && qq - k <= WINM1) {
          const float s = sc[fq][j];
          const float u = exp2f(s * 0.057707801635558534f);
          const float arg = 72.134752044448169f -
                            144.26950408889634f * __builtin_amdgcn_rcpf(u + 1.f);
          p = exp2f(arg);
        }
        const __hip_bfloat16 pb = __float2bfloat16(p);
        Ps[(wq * 16 + lg * 4 + j) * 72 + fq * 16 + lr] = pb;
        rsum[j] += __bfloat162float(pb);
      }
    }
#pragma unroll
    for (int ks2 = 0; ks2 < 2; ks2++) {
      s16x8 pa = *(const s16x8*)(Ps + (wq * 16 + lr) * 72 + ks2 * 32 + lg * 8);
#pragma unroll
      for (int f2 = 0; f2 < 16; f2++) {
        s16x8 vb = *(const s16x8*)(Vs + (f2 * 16 + lr) * 72 + ks2 * 32 + lg * 8);
        acc[f2] = __builtin_amdgcn_mfma_f32_16x16x32_bf16(pa, vb, acc[f2], 0, 0, 0);
      }
    }
    __syncthreads();
  }
#pragma unroll
  for (int j = 0; j < 4; j++) {
    float s = rsum[j];
#pragma unroll
    for (int off = 1; off < 16; off <<= 1) s += __shfl_xor(s, off, 64);
    rsum[j] = 1.f / s;
  }
#pragma unroll
  for (int f2 = 0; f2 < 16; f2++)
#pragma unroll
    for (int j = 0; j < 4; j++)
      O[(size_t)(qrow_base + j) * ODIM + h * DHEAD + f2 * 16 + lr] =
          __float2bfloat16(acc[f2][j] * rsum[j]);
}

// ---------------- launcher ----------------
extern "C" void kernel_launch(void* const* d_in, const int* in_sizes, int n_in,
                              void* d_out, int out_size, void* d_ws, size_t ws_size,
                              hipStream_t stream) {
  const float* hidden  = (const float*)d_in[0];
  const float* qkv_w   = (const float*)d_in[1];
  const float* o_w     = (const float*)d_in[2];
  const float* gate_w  = (const float*)d_in[3];
  const float* up_w    = (const float*)d_in[4];
  const float* down_w  = (const float*)d_in[5];
  const float* in_ln   = (const float*)d_in[6];
  const float* post_attn_ln = (const float*)d_in[7];
  const float* pre_ffw_ln   = (const float*)d_in[8];
  const float* post_ffw_ln  = (const float*)d_in[9];
  const float* cosb    = (const float*)d_in[10];
  const float* sinb    = (const float*)d_in[11];
  float* out = (float*)d_out;
  char* ws = (char*)d_ws;

  // ---- workspace layout (bytes); single reusable weight slot (146,276,352 total) ----
  const size_t OFF_W   = 0;
  const size_t OFF_HF  = 42467328;
  const size_t OFF_X   = 61341696;
  const size_t OFF_S1  = 70778880;
  const size_t OFF_S2  = 108527616;
  const size_t NEED    = 146276352;

  if (ws_size < NEED) {  // diagnostic: encode ws MiB into output
    k_fill<<<1024, 256, 0, stream>>>(out, 100000.0f + (float)(ws_size >> 20), (size_t)out_size);
    return;
  }

  __hip_bfloat16* W    = (__hip_bfloat16*)(ws + OFF_W);
  float*          Hf   = (float*)(ws + OFF_HF);
  __hip_bfloat16* Xb   = (__hip_bfloat16*)(ws + OFF_X);
  float*          QKV  = (float*)(ws + OFF_S1);
  __hip_bfloat16* GATEB= (__hip_bfloat16*)(ws + OFF_S1);
  float*          Yf   = (float*)(ws + OFF_S1);
  __hip_bfloat16* Qb   = (__hip_bfloat16*)(ws + OFF_S2);
  __hip_bfloat16* Kb   = (__hip_bfloat16*)(ws + OFF_S2 + 8388608);
  __hip_bfloat16* Vtb  = (__hip_bfloat16*)(ws + OFF_S2 + 12582912);
  __hip_bfloat16* ATTN = (__hip_bfloat16*)(ws + OFF_S2 + 29360128);
  float*          PROJ = (float*)(ws + OFF_S2);
  __hip_bfloat16* ACT  = (__hip_bfloat16*)(ws + OFF_S2);

  // 1. qkv weight -> W ; x = rmsnorm(hidden) -> Xb ; qkv = Xb @ W^T (f32)
  k_transpose_bf16<<<dim3(QKVN / 32, HIDDEN / 32), 256, 0, stream>>>(qkv_w, W, HIDDEN, QKVN);
  k_rmsnorm<false, true><<<S_LEN, 256, 0, stream>>>(hidden, in_ln, nullptr, Xb);
  k_gemm_bt<0><<<dim3(QKVN / 128, S_LEN / 128), 256, 0, stream>>>(Xb, W, QKV, nullptr, QKVN, HIDDEN);
  // 2. rope+split Q/K ; V extract+transpose
  k_rope_split<<<S_LEN, 256, 0, stream>>>(QKV, cosb, sinb, Qb, Kb);
  k_vsplit_t<<<dim3(S_LEN / 64, NKVH), 256, 0, stream>>>(QKV, Vtb);
  // 3. attention -> ATTN (bf16)
  k_attn_mfma<<<dim3(S_LEN / 64, NHEAD), 256, 0, stream>>>(Qb, Kb, Vtb, ATTN);
  // 4. o weight -> W ; proj = ATTN @ W^T (f32)
  k_transpose_bf16<<<dim3(HIDDEN / 32, ODIM / 32), 256, 0, stream>>>(o_w, W, ODIM, HIDDEN);
  k_gemm_bt<0><<<dim3(HIDDEN / 128, S_LEN / 128), 256, 0, stream>>>(ATTN, W, PROJ, nullptr, HIDDEN, ODIM);
  // 5. h = hidden + rmsnorm(proj) ; x2 = rmsnorm(h) -> Xb slot
  k_rmsnorm<true, false><<<S_LEN, 256, 0, stream>>>(PROJ, post_attn_ln, hidden, Hf);
  k_rmsnorm<false, true><<<S_LEN, 256, 0, stream>>>(Hf, pre_ffw_ln, nullptr, Xb);
  // 6. gate weight -> W ; gate = X2 @ W^T (bf16, pipelined 256^2)
  k_transpose_bf16<<<dim3(FFDIM / 32, HIDDEN / 32), 256, 0, stream>>>(gate_w, W, HIDDEN, FFDIM);
  k_gemm_p<1><<<dim3(FFDIM / 256, S_LEN / 256), 512, 0, stream>>>(Xb, W, GATEB, nullptr, FFDIM, HIDDEN);
  // 7. up weight -> W ; act = gelu(gate) * (X2 @ W^T) (bf16, fused epilogue, pipelined)
  k_transpose_bf16<<<dim3(FFDIM / 32, HIDDEN / 32), 256, 0, stream>>>(up_w, W, HIDDEN, FFDIM);
  k_gemm_p<2><<<dim3(FFDIM / 256, S_LEN / 256), 512, 0, stream>>>(Xb, W, ACT, GATEB, FFDIM, HIDDEN);
  // 8. down weight -> W ; y = ACT @ W^T (f32)
  k_transpose_bf16<<<dim3(HIDDEN / 32, FFDIM / 32), 256, 0, stream>>>(down_w, W, FFDIM, HIDDEN);
  k_gemm_bt<0><<<dim3(HIDDEN / 128, S_LEN / 128), 256, 0, stream>>>(ACT, W, Yf, nullptr, HIDDEN, FFDIM);
  // 9. out = h + rmsnorm(y)
  k_rmsnorm<true, false><<<S_LEN, 256, 0, stream>>>(Yf, post_ffw_ln, Hf, out);
}